// Round 2
// baseline (288.918 us; speedup 1.0000x reference)
//
#include <hip/hip_runtime.h>
#include <cstddef>

#define N_ENT   2000
#define GAT_EMB 64
#define GAT_HID 3
#define HIDDEN  256
#define BATCH   8
#define ALPHA   0.2f

// out[b,k] = fc1_b[k]  (atomicAdd target; d_out is poisoned before every launch)
__global__ __launch_bounds__(256) void k_init(const float* __restrict__ fc1_b,
                                              float* __restrict__ out) {
    int idx = blockIdx.x * 256 + threadIdx.x;   // [0, 2048)
    out[idx] = fc1_b[idx & (HIDDEN - 1)];
}

// One block per 2 entities (i0, i0+1), all 8 batches. No workspace use at all.
__global__ __launch_bounds__(256) void k_main(const float* __restrict__ emb,
                                              const float* __restrict__ W,
                                              const float* __restrict__ a,
                                              const float* __restrict__ fc1_w,
                                              const int*   __restrict__ adj,
                                              float* __restrict__ out) {
    __shared__ float4 spack[N_ENT];   // (s2, h0, h1, h2) per entity: 32000 B
    __shared__ float  sW[GAT_EMB * GAT_HID];
    __shared__ float  sa[2 * GAT_HID];
    __shared__ float  s1_own[2];      // s1 for the block's two entities
    __shared__ float  xblk[BATCH][8]; // x[b][3*di + d], d<3, di<2 (padded to 8)

    int t  = threadIdx.x;
    int g  = blockIdx.x;
    int i0 = g * 2;

    if (t < GAT_EMB * GAT_HID) sW[t] = W[t];
    if (t < 2 * GAT_HID)       sa[t] = a[t];
    __syncthreads();

    // ---- Phase 1: h = emb@W, s2, (s1 for own rows) -> LDS ----
    for (int j = t; j < N_ENT; j += 256) {
        const float4* er = (const float4*)(emb + (size_t)j * GAT_EMB);
        float h0 = 0.f, h1 = 0.f, h2 = 0.f;
#pragma unroll
        for (int k4 = 0; k4 < GAT_EMB / 4; ++k4) {
            float4 e4 = er[k4];
            int k = 4 * k4;
            h0 += e4.x * sW[(k + 0) * 3 + 0]; h1 += e4.x * sW[(k + 0) * 3 + 1]; h2 += e4.x * sW[(k + 0) * 3 + 2];
            h0 += e4.y * sW[(k + 1) * 3 + 0]; h1 += e4.y * sW[(k + 1) * 3 + 1]; h2 += e4.y * sW[(k + 1) * 3 + 2];
            h0 += e4.z * sW[(k + 2) * 3 + 0]; h1 += e4.z * sW[(k + 2) * 3 + 1]; h2 += e4.z * sW[(k + 2) * 3 + 2];
            h0 += e4.w * sW[(k + 3) * 3 + 0]; h1 += e4.w * sW[(k + 3) * 3 + 1]; h2 += e4.w * sW[(k + 3) * 3 + 2];
        }
        float s2 = h0 * sa[3] + h1 * sa[4] + h2 * sa[5];
        spack[j] = make_float4(s2, h0, h1, h2);
        if (j == i0 || j == i0 + 1)
            s1_own[j - i0] = h0 * sa[0] + h1 * sa[1] + h2 * sa[2];
    }
    __syncthreads();

    // ---- Phase 2: masked-softmax attention + aggregation + ELU ----
    // 16 (b, di) rows; wave w handles sub = w*4 + r.
    int lane = t & 63;
    int w    = t >> 6;
    for (int r = 0; r < 4; ++r) {
        int sub = w * 4 + r;        // [0,16)
        int b   = sub >> 1;
        int di  = sub & 1;
        int i   = i0 + di;
        float s1v = s1_own[di];
        const int4* __restrict__ arow =
            (const int4*)(adj + ((size_t)b * N_ENT + i) * N_ENT);

        float asum = 0.f, ax = 0.f, ay = 0.f, az = 0.f;
        for (int jj = lane; jj < N_ENT / 4; jj += 64) {   // 500 int4 per row, exact
            int4 av = arow[jj];
            int jb = jj * 4;
#pragma unroll
            for (int q = 0; q < 4; ++q) {
                int m = (q == 0) ? av.x : (q == 1) ? av.y : (q == 2) ? av.z : av.w;
                float4 p = spack[jb + q];
                float e  = s1v + p.x;
                float lr = fmaxf(e, 0.f) + ALPHA * fminf(e, 0.f);
                float ev = (m > 0) ? __expf(lr) : 1.0f;  // expf(9e-15) == 1.0f exactly
                asum += ev;
                ax += ev * p.y;
                ay += ev * p.z;
                az += ev * p.w;
            }
        }
#pragma unroll
        for (int off = 32; off > 0; off >>= 1) {
            asum += __shfl_xor(asum, off, 64);
            ax   += __shfl_xor(ax,   off, 64);
            ay   += __shfl_xor(ay,   off, 64);
            az   += __shfl_xor(az,   off, 64);
        }
        if (lane == 0) {
            float inv = 1.0f / asum;
            float p0 = ax * inv, p1 = ay * inv, p2 = az * inv;
            p0 = (p0 > 0.f) ? p0 : expm1f(p0);   // ELU
            p1 = (p1 > 0.f) ? p1 : expm1f(p1);
            p2 = (p2 > 0.f) ? p2 : expm1f(p2);
            xblk[b][3 * di + 0] = p0;
            xblk[b][3 * di + 1] = p1;
            xblk[b][3 * di + 2] = p2;
        }
    }
    __syncthreads();

    // ---- Phase 3: FC contribution of columns m = 6g .. 6g+5, one k per thread ----
    {
        int k = t;  // [0,256)
        const float* __restrict__ wr = fc1_w + (size_t)k * (N_ENT * GAT_HID) + 3 * i0;
        // 3*i0 = 6g is even -> float2-aligned
        const float2* wr2 = (const float2*)wr;
        float2 w01 = wr2[0], w23 = wr2[1], w45 = wr2[2];
#pragma unroll
        for (int b = 0; b < BATCH; ++b) {
            float d = xblk[b][0] * w01.x + xblk[b][1] * w01.y
                    + xblk[b][2] * w23.x + xblk[b][3] * w23.y
                    + xblk[b][4] * w45.x + xblk[b][5] * w45.y;
            atomicAdd(&out[b * HIDDEN + k], d);
        }
    }
}

extern "C" void kernel_launch(void* const* d_in, const int* in_sizes, int n_in,
                              void* d_out, int out_size, void* d_ws, size_t ws_size,
                              hipStream_t stream) {
    const float* emb   = (const float*)d_in[0];
    const float* W     = (const float*)d_in[1];
    const float* a     = (const float*)d_in[2];
    const float* fc1_w = (const float*)d_in[3];
    const float* fc1_b = (const float*)d_in[4];
    const int*   adj   = (const int*)d_in[5];
    float* out = (float*)d_out;
    (void)d_ws; (void)ws_size;

    k_init<<<8, 256, 0, stream>>>(fc1_b, out);
    k_main<<<N_ENT / 2, 256, 0, stream>>>(emb, W, a, fc1_w, adj, out);
}

// Round 3
// 242.597 us; speedup vs baseline: 1.1909x; 1.1909x over previous
//
#include <hip/hip_runtime.h>
#include <cstddef>

#define N_ENT   2000
#define GAT_EMB 64
#define GAT_HID 3
#define HIDDEN  256
#define BATCH   8
#define ALPHA   0.2f

// ws layout (floats): [0..8191] pack float4[2048] = {s2,h0,h1,h2}; [8192..10239] s1.
// Total 40,960 bytes. Only used if ws_size >= that (round-1 lesson: never exceed ws_size).
#define WS_S1_F   8192
#define WS_BYTES  40960

__global__ __launch_bounds__(256) void k_init(const float* __restrict__ fc1_b,
                                              float* __restrict__ out) {
    int idx = blockIdx.x * 256 + threadIdx.x;   // [0, 2048)
    out[idx] = fc1_b[idx & (HIDDEN - 1)];
}

// pack[j] = {s2[j], h0, h1, h2}, s1[j] -> ws  (tiny: 2000 rows)
__global__ __launch_bounds__(256) void k_prep(const float* __restrict__ emb,
                                              const float* __restrict__ W,
                                              const float* __restrict__ a,
                                              float* __restrict__ ws) {
    __shared__ float sW[GAT_EMB * GAT_HID];
    __shared__ float sa[2 * GAT_HID];
    int t = threadIdx.x;
    if (t < GAT_EMB * GAT_HID) sW[t] = W[t];
    if (t < 2 * GAT_HID)       sa[t] = a[t];
    __syncthreads();
    int i = blockIdx.x * 256 + t;
    if (i >= N_ENT) return;
    const float4* er = (const float4*)(emb + (size_t)i * GAT_EMB);
    float h0 = 0.f, h1 = 0.f, h2 = 0.f;
#pragma unroll
    for (int k4 = 0; k4 < GAT_EMB / 4; ++k4) {
        float4 e4 = er[k4];
        int k = 4 * k4;
        h0 += e4.x * sW[(k + 0) * 3 + 0]; h1 += e4.x * sW[(k + 0) * 3 + 1]; h2 += e4.x * sW[(k + 0) * 3 + 2];
        h0 += e4.y * sW[(k + 1) * 3 + 0]; h1 += e4.y * sW[(k + 1) * 3 + 1]; h2 += e4.y * sW[(k + 1) * 3 + 2];
        h0 += e4.z * sW[(k + 2) * 3 + 0]; h1 += e4.z * sW[(k + 2) * 3 + 1]; h2 += e4.z * sW[(k + 2) * 3 + 2];
        h0 += e4.w * sW[(k + 3) * 3 + 0]; h1 += e4.w * sW[(k + 3) * 3 + 1]; h2 += e4.w * sW[(k + 3) * 3 + 2];
    }
    ((float4*)ws)[i] = make_float4(h0 * sa[3] + h1 * sa[4] + h2 * sa[5], h0, h1, h2);
    ws[WS_S1_F + i] = h0 * sa[0] + h1 * sa[1] + h2 * sa[2];
}

// One block per 2 entities. Wave w: entity i0+(w>>1), batches 4*(w&1)..+3.
// Per j: 4 independent adj streams (wave-uniform bases), 1 LDS b128 (lane-contiguous,
// conflict-free), 1 exp shared by 4 batches.
__global__ __launch_bounds__(256) void k_main(const float* __restrict__ emb,
                                              const float* __restrict__ W,
                                              const float* __restrict__ a,
                                              const float* __restrict__ fc1_w,
                                              const int*   __restrict__ adj,
                                              const float* __restrict__ wsrc,
                                              int use_ws,
                                              float* __restrict__ out) {
    __shared__ float4 spack[N_ENT];   // 32000 B
    __shared__ float  sW[GAT_EMB * GAT_HID];
    __shared__ float  sa[2 * GAT_HID];
    __shared__ float  s1_own[2];
    __shared__ float  xblk[BATCH][8];

    int t  = threadIdx.x;
    int i0 = blockIdx.x * 2;

    if (use_ws) {
        const float4* src = (const float4*)wsrc;
        for (int j = t; j < N_ENT; j += 256) spack[j] = src[j];
        if (t < 2) s1_own[t] = wsrc[WS_S1_F + i0 + t];
    } else {
        if (t < GAT_EMB * GAT_HID) sW[t] = W[t];
        if (t < 2 * GAT_HID)       sa[t] = a[t];
        __syncthreads();
        for (int j = t; j < N_ENT; j += 256) {
            const float4* er = (const float4*)(emb + (size_t)j * GAT_EMB);
            float h0 = 0.f, h1 = 0.f, h2 = 0.f;
#pragma unroll
            for (int k4 = 0; k4 < GAT_EMB / 4; ++k4) {
                float4 e4 = er[k4];
                int k = 4 * k4;
                h0 += e4.x * sW[(k + 0) * 3 + 0]; h1 += e4.x * sW[(k + 0) * 3 + 1]; h2 += e4.x * sW[(k + 0) * 3 + 2];
                h0 += e4.y * sW[(k + 1) * 3 + 0]; h1 += e4.y * sW[(k + 1) * 3 + 1]; h2 += e4.y * sW[(k + 1) * 3 + 2];
                h0 += e4.z * sW[(k + 2) * 3 + 0]; h1 += e4.z * sW[(k + 2) * 3 + 1]; h2 += e4.z * sW[(k + 2) * 3 + 2];
                h0 += e4.w * sW[(k + 3) * 3 + 0]; h1 += e4.w * sW[(k + 3) * 3 + 1]; h2 += e4.w * sW[(k + 3) * 3 + 2];
            }
            spack[j] = make_float4(h0 * sa[3] + h1 * sa[4] + h2 * sa[5], h0, h1, h2);
            if (j == i0 || j == i0 + 1)
                s1_own[j - i0] = h0 * sa[0] + h1 * sa[1] + h2 * sa[2];
        }
    }
    __syncthreads();

    // ---- Phase 2 ----
    int lane = t & 63;
    int w    = t >> 6;
    int di   = w >> 1;
    int b0   = (w & 1) * 4;
    int i    = i0 + di;
    float s1v = s1_own[di];
    const int* __restrict__ r0 = adj + ((size_t)(b0 + 0) * N_ENT + i) * N_ENT;
    const int* __restrict__ r1 = adj + ((size_t)(b0 + 1) * N_ENT + i) * N_ENT;
    const int* __restrict__ r2 = adj + ((size_t)(b0 + 2) * N_ENT + i) * N_ENT;
    const int* __restrict__ r3 = adj + ((size_t)(b0 + 3) * N_ENT + i) * N_ENT;

    float as0 = 0.f, x0 = 0.f, y0 = 0.f, z0 = 0.f;
    float as1 = 0.f, x1 = 0.f, y1 = 0.f, z1 = 0.f;
    float as2 = 0.f, x2 = 0.f, y2 = 0.f, z2 = 0.f;
    float as3 = 0.f, x3 = 0.f, y3 = 0.f, z3 = 0.f;

#pragma unroll 2
    for (int k = 0; k < (N_ENT + 63) / 64; ++k) {
        int j = lane + 64 * k;
        if (j < N_ENT) {
            int m0 = r0[j], m1 = r1[j], m2 = r2[j], m3 = r3[j];
            float4 p = spack[j];                       // lane-contiguous: conflict-free
            float e  = s1v + p.x;
            float lr = fmaxf(e, 0.f) + ALPHA * fminf(e, 0.f);
            float ev = __expf(lr);                     // expf(9e-15)==1.0f for masked
            float e0 = (m0 > 0) ? ev : 1.0f;
            float e1 = (m1 > 0) ? ev : 1.0f;
            float e2 = (m2 > 0) ? ev : 1.0f;
            float e3 = (m3 > 0) ? ev : 1.0f;
            as0 += e0; x0 += e0 * p.y; y0 += e0 * p.z; z0 += e0 * p.w;
            as1 += e1; x1 += e1 * p.y; y1 += e1 * p.z; z1 += e1 * p.w;
            as2 += e2; x2 += e2 * p.y; y2 += e2 * p.z; z2 += e2 * p.w;
            as3 += e3; x3 += e3 * p.y; y3 += e3 * p.z; z3 += e3 * p.w;
        }
    }
#pragma unroll
    for (int off = 32; off > 0; off >>= 1) {
        as0 += __shfl_xor(as0, off, 64); x0 += __shfl_xor(x0, off, 64);
        y0  += __shfl_xor(y0,  off, 64); z0 += __shfl_xor(z0, off, 64);
        as1 += __shfl_xor(as1, off, 64); x1 += __shfl_xor(x1, off, 64);
        y1  += __shfl_xor(y1,  off, 64); z1 += __shfl_xor(z1, off, 64);
        as2 += __shfl_xor(as2, off, 64); x2 += __shfl_xor(x2, off, 64);
        y2  += __shfl_xor(y2,  off, 64); z2 += __shfl_xor(z2, off, 64);
        as3 += __shfl_xor(as3, off, 64); x3 += __shfl_xor(x3, off, 64);
        y3  += __shfl_xor(y3,  off, 64); z3 += __shfl_xor(z3, off, 64);
    }
    if (lane == 0) {
        float inv, p0, p1, p2;
        inv = 1.f / as0; p0 = x0 * inv; p1 = y0 * inv; p2 = z0 * inv;
        xblk[b0+0][3*di+0] = (p0 > 0.f) ? p0 : expm1f(p0);
        xblk[b0+0][3*di+1] = (p1 > 0.f) ? p1 : expm1f(p1);
        xblk[b0+0][3*di+2] = (p2 > 0.f) ? p2 : expm1f(p2);
        inv = 1.f / as1; p0 = x1 * inv; p1 = y1 * inv; p2 = z1 * inv;
        xblk[b0+1][3*di+0] = (p0 > 0.f) ? p0 : expm1f(p0);
        xblk[b0+1][3*di+1] = (p1 > 0.f) ? p1 : expm1f(p1);
        xblk[b0+1][3*di+2] = (p2 > 0.f) ? p2 : expm1f(p2);
        inv = 1.f / as2; p0 = x2 * inv; p1 = y2 * inv; p2 = z2 * inv;
        xblk[b0+2][3*di+0] = (p0 > 0.f) ? p0 : expm1f(p0);
        xblk[b0+2][3*di+1] = (p1 > 0.f) ? p1 : expm1f(p1);
        xblk[b0+2][3*di+2] = (p2 > 0.f) ? p2 : expm1f(p2);
        inv = 1.f / as3; p0 = x3 * inv; p1 = y3 * inv; p2 = z3 * inv;
        xblk[b0+3][3*di+0] = (p0 > 0.f) ? p0 : expm1f(p0);
        xblk[b0+3][3*di+1] = (p1 > 0.f) ? p1 : expm1f(p1);
        xblk[b0+3][3*di+2] = (p2 > 0.f) ? p2 : expm1f(p2);
    }
    __syncthreads();

    // ---- Phase 3: FC columns m = 6g..6g+5, one k per thread ----
    {
        int k = t;
        const float2* wr2 = (const float2*)(fc1_w + (size_t)k * (N_ENT * GAT_HID) + 3 * i0);
        float2 w01 = wr2[0], w23 = wr2[1], w45 = wr2[2];
#pragma unroll
        for (int b = 0; b < BATCH; ++b) {
            float d = xblk[b][0] * w01.x + xblk[b][1] * w01.y
                    + xblk[b][2] * w23.x + xblk[b][3] * w23.y
                    + xblk[b][4] * w45.x + xblk[b][5] * w45.y;
            atomicAdd(&out[b * HIDDEN + k], d);
        }
    }
}

extern "C" void kernel_launch(void* const* d_in, const int* in_sizes, int n_in,
                              void* d_out, int out_size, void* d_ws, size_t ws_size,
                              hipStream_t stream) {
    const float* emb   = (const float*)d_in[0];
    const float* W     = (const float*)d_in[1];
    const float* a     = (const float*)d_in[2];
    const float* fc1_w = (const float*)d_in[3];
    const float* fc1_b = (const float*)d_in[4];
    const int*   adj   = (const int*)d_in[5];
    float* out = (float*)d_out;
    float* ws  = (float*)d_ws;

    int use_ws = (ws_size >= (size_t)WS_BYTES) ? 1 : 0;  // constant across calls
    k_init<<<8, 256, 0, stream>>>(fc1_b, out);
    if (use_ws) k_prep<<<8, 256, 0, stream>>>(emb, W, a, ws);
    k_main<<<N_ENT / 2, 256, 0, stream>>>(emb, W, a, fc1_w, adj, ws, use_ws, out);
}

// Round 4
// 218.001 us; speedup vs baseline: 1.3253x; 1.1128x over previous
//
#include <hip/hip_runtime.h>
#include <cstddef>

#define N_ENT   2000
#define NPAD    2048
#define GAT_EMB 64
#define GAT_HID 3
#define HIDDEN  256
#define BATCH   8
#define ALPHA   0.2f

// ws layout (floats, SoA): [0]=s2[2048] [2048]=h0 [4096]=h1 [6144]=h2 [8192]=s1[2048]
// Total 40,960 bytes; only used when ws_size allows (round-1 lesson).
#define WS_BYTES  40960

__global__ __launch_bounds__(256) void k_init(const float* __restrict__ fc1_b,
                                              float* __restrict__ out) {
    int idx = blockIdx.x * 256 + threadIdx.x;   // [0, 2048)
    out[idx] = fc1_b[idx & (HIDDEN - 1)];
}

__global__ __launch_bounds__(256) void k_prep(const float* __restrict__ emb,
                                              const float* __restrict__ W,
                                              const float* __restrict__ a,
                                              float* __restrict__ ws) {
    __shared__ float sW[GAT_EMB * GAT_HID];
    __shared__ float sa[2 * GAT_HID];
    int t = threadIdx.x;
    if (t < GAT_EMB * GAT_HID) sW[t] = W[t];
    if (t < 2 * GAT_HID)       sa[t] = a[t];
    __syncthreads();
    int i = blockIdx.x * 256 + t;
    if (i >= N_ENT) return;
    const float4* er = (const float4*)(emb + (size_t)i * GAT_EMB);
    float h0 = 0.f, h1 = 0.f, h2 = 0.f;
#pragma unroll
    for (int k4 = 0; k4 < GAT_EMB / 4; ++k4) {
        float4 e4 = er[k4];
        int k = 4 * k4;
        h0 += e4.x * sW[(k + 0) * 3 + 0]; h1 += e4.x * sW[(k + 0) * 3 + 1]; h2 += e4.x * sW[(k + 0) * 3 + 2];
        h0 += e4.y * sW[(k + 1) * 3 + 0]; h1 += e4.y * sW[(k + 1) * 3 + 1]; h2 += e4.y * sW[(k + 1) * 3 + 2];
        h0 += e4.z * sW[(k + 2) * 3 + 0]; h1 += e4.z * sW[(k + 2) * 3 + 1]; h2 += e4.z * sW[(k + 2) * 3 + 2];
        h0 += e4.w * sW[(k + 3) * 3 + 0]; h1 += e4.w * sW[(k + 3) * 3 + 1]; h2 += e4.w * sW[(k + 3) * 3 + 2];
    }
    ws[0 * NPAD + i] = h0 * sa[3] + h1 * sa[4] + h2 * sa[5];  // s2
    ws[1 * NPAD + i] = h0;
    ws[2 * NPAD + i] = h1;
    ws[3 * NPAD + i] = h2;
    ws[4 * NPAD + i] = h0 * sa[0] + h1 * sa[1] + h2 * sa[2];  // s1
}

// One block per 4 entities; wave w owns entity i0+w across ALL 8 batches:
// 8 independent wave-uniform adj streams, dwordx4 loads (1 KB/wave-instr),
// lane-contiguous b128 LDS reads (conflict-free), 4 exps amortized over 8 batches.
__global__ __launch_bounds__(256) void k_main(const float* __restrict__ emb,
                                              const float* __restrict__ W,
                                              const float* __restrict__ a,
                                              const float* __restrict__ fc1_w,
                                              const int*   __restrict__ adj,
                                              const float* __restrict__ wsrc,
                                              int use_ws,
                                              float* __restrict__ out) {
    __shared__ __align__(16) float s2s[NPAD];
    __shared__ __align__(16) float h0s[NPAD];
    __shared__ __align__(16) float h1s[NPAD];
    __shared__ __align__(16) float h2s[NPAD];
    __shared__ float sW[GAT_EMB * GAT_HID];
    __shared__ float sa[2 * GAT_HID];
    __shared__ float s1_own[4];
    __shared__ float xblk[BATCH][16];   // [b][3*w + d]

    int t  = threadIdx.x;
    int i0 = blockIdx.x * 4;

    if (use_ws) {
        const float4* s = (const float4*)wsrc;
        for (int idx = t; idx < N_ENT / 4; idx += 256) {   // 500 float4 per array
            ((float4*)s2s)[idx] = s[0 * (NPAD / 4) + idx];
            ((float4*)h0s)[idx] = s[1 * (NPAD / 4) + idx];
            ((float4*)h1s)[idx] = s[2 * (NPAD / 4) + idx];
            ((float4*)h2s)[idx] = s[3 * (NPAD / 4) + idx];
        }
        if (t < 4) s1_own[t] = wsrc[4 * NPAD + i0 + t];
    } else {
        if (t < GAT_EMB * GAT_HID) sW[t] = W[t];
        if (t < 2 * GAT_HID)       sa[t] = a[t];
        __syncthreads();
        for (int j = t; j < N_ENT; j += 256) {
            const float4* er = (const float4*)(emb + (size_t)j * GAT_EMB);
            float h0 = 0.f, h1 = 0.f, h2 = 0.f;
#pragma unroll
            for (int k4 = 0; k4 < GAT_EMB / 4; ++k4) {
                float4 e4 = er[k4];
                int k = 4 * k4;
                h0 += e4.x * sW[(k + 0) * 3 + 0]; h1 += e4.x * sW[(k + 0) * 3 + 1]; h2 += e4.x * sW[(k + 0) * 3 + 2];
                h0 += e4.y * sW[(k + 1) * 3 + 0]; h1 += e4.y * sW[(k + 1) * 3 + 1]; h2 += e4.y * sW[(k + 1) * 3 + 2];
                h0 += e4.z * sW[(k + 2) * 3 + 0]; h1 += e4.z * sW[(k + 2) * 3 + 1]; h2 += e4.z * sW[(k + 2) * 3 + 2];
                h0 += e4.w * sW[(k + 3) * 3 + 0]; h1 += e4.w * sW[(k + 3) * 3 + 1]; h2 += e4.w * sW[(k + 3) * 3 + 2];
            }
            s2s[j] = h0 * sa[3] + h1 * sa[4] + h2 * sa[5];
            h0s[j] = h0; h1s[j] = h1; h2s[j] = h2;
            if (j >= i0 && j < i0 + 4)
                s1_own[j - i0] = h0 * sa[0] + h1 * sa[1] + h2 * sa[2];
        }
    }
    __syncthreads();

    // ---- Phase 2: one entity per wave, 8 batch streams ----
    int lane = t & 63;
    int w    = t >> 6;
    int i    = i0 + w;
    float s1v = s1_own[w];
    const int* __restrict__ base = adj + (size_t)i * N_ENT;  // + b*N_ENT*N_ENT per stream

    float acc[BATCH][4];
#pragma unroll
    for (int b = 0; b < BATCH; ++b) { acc[b][0] = 0.f; acc[b][1] = 0.f; acc[b][2] = 0.f; acc[b][3] = 0.f; }

#pragma unroll 1
    for (int k = 0; k < (N_ENT + 255) / 256; ++k) {
        int j0 = k * 256 + lane * 4;
        if (j0 < N_ENT) {   // last iter: lanes 0..51 only (2000 = 7*256 + 52*4 exactly)
            int4 m[BATCH];
#pragma unroll
            for (int b = 0; b < BATCH; ++b)
                m[b] = *(const int4*)(base + (size_t)b * (N_ENT * N_ENT) + j0);
            float4 s2v = *(const float4*)&s2s[j0];
            float4 h0v = *(const float4*)&h0s[j0];
            float4 h1v = *(const float4*)&h1s[j0];
            float4 h2v = *(const float4*)&h2s[j0];
            float ev[4];
#pragma unroll
            for (int q = 0; q < 4; ++q) {
                float e  = s1v + ((const float*)&s2v)[q];
                float lr = fmaxf(e, 0.f) + ALPHA * fminf(e, 0.f);
                ev[q] = __expf(lr);         // expf(9e-15f) == 1.0f for masked entries
            }
#pragma unroll
            for (int b = 0; b < BATCH; ++b) {
                const int* mb = (const int*)&m[b];
#pragma unroll
                for (int q = 0; q < 4; ++q) {
                    float e = (mb[q] > 0) ? ev[q] : 1.0f;
                    acc[b][0] += e;
                    acc[b][1] += e * ((const float*)&h0v)[q];
                    acc[b][2] += e * ((const float*)&h1v)[q];
                    acc[b][3] += e * ((const float*)&h2v)[q];
                }
            }
        }
    }

#pragma unroll
    for (int off = 32; off > 0; off >>= 1)
#pragma unroll
        for (int b = 0; b < BATCH; ++b) {
            acc[b][0] += __shfl_xor(acc[b][0], off, 64);
            acc[b][1] += __shfl_xor(acc[b][1], off, 64);
            acc[b][2] += __shfl_xor(acc[b][2], off, 64);
            acc[b][3] += __shfl_xor(acc[b][3], off, 64);
        }

    if (lane == 0) {
#pragma unroll
        for (int b = 0; b < BATCH; ++b) {
            float inv = 1.f / acc[b][0];
            float p0 = acc[b][1] * inv, p1 = acc[b][2] * inv, p2 = acc[b][3] * inv;
            xblk[b][3 * w + 0] = (p0 > 0.f) ? p0 : expm1f(p0);   // ELU
            xblk[b][3 * w + 1] = (p1 > 0.f) ? p1 : expm1f(p1);
            xblk[b][3 * w + 2] = (p2 > 0.f) ? p2 : expm1f(p2);
        }
    }
    __syncthreads();

    // ---- Phase 3: FC columns m = 12*blk .. +11, one k per thread ----
    {
        int k = t;
        const float4* wr4 = (const float4*)(fc1_w + (size_t)k * (N_ENT * GAT_HID) + 3 * i0);
        float4 wa = wr4[0], wb = wr4[1], wc = wr4[2];
#pragma unroll
        for (int b = 0; b < BATCH; ++b) {
            float d = xblk[b][0]  * wa.x + xblk[b][1]  * wa.y + xblk[b][2]  * wa.z + xblk[b][3]  * wa.w
                    + xblk[b][4]  * wb.x + xblk[b][5]  * wb.y + xblk[b][6]  * wb.z + xblk[b][7]  * wb.w
                    + xblk[b][8]  * wc.x + xblk[b][9]  * wc.y + xblk[b][10] * wc.z + xblk[b][11] * wc.w;
            atomicAdd(&out[b * HIDDEN + k], d);
        }
    }
}

extern "C" void kernel_launch(void* const* d_in, const int* in_sizes, int n_in,
                              void* d_out, int out_size, void* d_ws, size_t ws_size,
                              hipStream_t stream) {
    const float* emb   = (const float*)d_in[0];
    const float* W     = (const float*)d_in[1];
    const float* a     = (const float*)d_in[2];
    const float* fc1_w = (const float*)d_in[3];
    const float* fc1_b = (const float*)d_in[4];
    const int*   adj   = (const int*)d_in[5];
    float* out = (float*)d_out;
    float* ws  = (float*)d_ws;

    int use_ws = (ws_size >= (size_t)WS_BYTES) ? 1 : 0;  // constant across calls
    k_init<<<8, 256, 0, stream>>>(fc1_b, out);
    if (use_ws) k_prep<<<8, 256, 0, stream>>>(emb, W, a, ws);
    k_main<<<N_ENT / 4, 256, 0, stream>>>(emb, W, a, fc1_w, adj, ws, use_ws, out);
}